// Round 1
// 719.088 us; speedup vs baseline: 1.0349x; 1.0349x over previous
//
#include <hip/hip_runtime.h>
#include <math.h>

// Problem constants: S=1024, B=128, E=1024, DH=1024, OUT=1024
#define SS 1024
#define BB 128
#define EE 1024
#define DHH 1024
#define OO 1024
#define NCHUNK 8
#define ROWS_PER_CHUNK (SS / NCHUNK)            // 128
#define NWAVES 4
#define ROWS_PER_WAVE (ROWS_PER_CHUNK / NWAVES) // 32
#define ZSPLIT 16                               // split-K factor for both GEMMs

// ---------------------------------------------------------------------------
// GEMM (NT): part[z][m][n] = sum_{k in z-slice} A[m][k] * B[n][k]
// 64x64 tile, 256 threads, 4x4 micro-tile, k-major LDS so fragment reads are
// ds_read_b128 (16 FMA per 2 LDS instrs). Register-prefetch double buffer.
// No atomics: partials go to workspace, reduced by reduce_splitk.
// ---------------------------------------------------------------------------
__global__ __launch_bounds__(256) void gemm_nt_partk(const float* __restrict__ A,
                                                     const float* __restrict__ B,
                                                     float* __restrict__ part,
                                                     int M, int N, int K, int Kc) {
    __shared__ float As[32][68];   // [k][m], pad 68: rows 16B-aligned, ~2-way banks (free)
    __shared__ float Bs[32][68];   // [k][n]
    const int n0 = blockIdx.x * 64;
    const int m0 = blockIdx.y * 64;
    const int z  = blockIdx.z;
    const int k0 = z * Kc;
    const int tid = threadIdx.x;
    const int r  = tid & 63;          // tile row for staging (0..63)
    const int kc = (tid >> 6) << 2;   // k sub-col 0,4,8,12 (plus +16 pair)
    const int tm = ((tid >> 4) & 15) << 2;  // 0,4,..,60
    const int tn = (tid & 15) << 2;         // 0,4,..,60

    const float* Ap = A + (size_t)(m0 + r) * K + k0;
    const float* Bp = B + (size_t)(n0 + r) * K + k0;

    float4 a0 = *(const float4*)(Ap + kc);
    float4 a1 = *(const float4*)(Ap + 16 + kc);
    float4 b0 = *(const float4*)(Bp + kc);
    float4 b1 = *(const float4*)(Bp + 16 + kc);

    float acc[4][4] = {};
    const int nkt = Kc >> 5;
    for (int kt = 0; kt < nkt; ++kt) {
        __syncthreads();   // previous compute done before LDS overwrite
        As[kc + 0][r] = a0.x; As[kc + 1][r] = a0.y; As[kc + 2][r] = a0.z; As[kc + 3][r] = a0.w;
        As[kc + 16][r] = a1.x; As[kc + 17][r] = a1.y; As[kc + 18][r] = a1.z; As[kc + 19][r] = a1.w;
        Bs[kc + 0][r] = b0.x; Bs[kc + 1][r] = b0.y; Bs[kc + 2][r] = b0.z; Bs[kc + 3][r] = b0.w;
        Bs[kc + 16][r] = b1.x; Bs[kc + 17][r] = b1.y; Bs[kc + 18][r] = b1.z; Bs[kc + 19][r] = b1.w;

        float4 na0 = make_float4(0.f, 0.f, 0.f, 0.f), na1 = na0, nb0 = na0, nb1 = na0;
        if (kt + 1 < nkt) {   // prefetch next k-tile; overlaps the FMA phase below
            const float* Ap2 = Ap + ((kt + 1) << 5);
            const float* Bp2 = Bp + ((kt + 1) << 5);
            na0 = *(const float4*)(Ap2 + kc);
            na1 = *(const float4*)(Ap2 + 16 + kc);
            nb0 = *(const float4*)(Bp2 + kc);
            nb1 = *(const float4*)(Bp2 + 16 + kc);
        }
        __syncthreads();
#pragma unroll
        for (int j = 0; j < 32; ++j) {
            const float4 av = *(const float4*)&As[j][tm];
            const float4 bv = *(const float4*)&Bs[j][tn];
            const float a_[4] = {av.x, av.y, av.z, av.w};
            const float b_[4] = {bv.x, bv.y, bv.z, bv.w};
#pragma unroll
            for (int i = 0; i < 4; ++i)
#pragma unroll
                for (int jj = 0; jj < 4; ++jj)
                    acc[i][jj] = fmaf(a_[i], b_[jj], acc[i][jj]);
        }
        a0 = na0; a1 = na1; b0 = nb0; b1 = nb1;
    }

    float* P = part + ((size_t)z * M + m0 + tm) * N + n0 + tn;
#pragma unroll
    for (int i = 0; i < 4; ++i) {
        float4 v = make_float4(acc[i][0], acc[i][1], acc[i][2], acc[i][3]);
        *(float4*)(P + (size_t)i * N) = v;
    }
}

// dst[m][n] = bias[n] + sum_z part[z][m][n]    (N = 1024 fixed, float4-wide)
__global__ __launch_bounds__(256) void reduce_splitk(const float* __restrict__ part,
                                                     const float* __restrict__ bias,
                                                     float* __restrict__ dst,
                                                     int MN4, int Z) {
    const int i = blockIdx.x * 256 + threadIdx.x;   // float4 index
    if (i >= MN4) return;
    float4 s = ((const float4*)bias)[i & 255];      // N/4 = 256
    for (int zz = 0; zz < Z; ++zz) {
        float4 v = ((const float4*)part)[(size_t)zz * MN4 + i];
        s.x += v.x; s.y += v.y; s.z += v.z; s.w += v.w;
    }
    ((float4*)dst)[i] = s;
}

// ---------------------------------------------------------------------------
// Flash attention, one pass over ingr[S,B,E]. Per (chunk,b) block, 4 waves.
// v2: 2-row batches with one-batch-ahead prefetch (8KB in flight per wave),
// one max/rescale per batch (3 VALU/elem vs 4), interleaved dual reduce.
// ---------------------------------------------------------------------------
__global__ __launch_bounds__(256) void flash_attn_kernel(
        const float* __restrict__ ingr,   // [S,B,E]
        const float* __restrict__ dh,     // [B,E]
        float* __restrict__ pctx,         // [B,NCHUNK,E]  (unnormalized)
        float* __restrict__ pml)          // [B,NCHUNK,2]  (m, l)
{
    const int chunk = blockIdx.x;
    const int b = blockIdx.y;
    const int tid = threadIdx.x;
    const int wave = tid >> 6;
    const int lane = tid & 63;

    const float* dhb = dh + (size_t)b * EE + (lane << 2);
    const float4 d0 = *(const float4*)(dhb);
    const float4 d1 = *(const float4*)(dhb + 256);
    const float4 d2 = *(const float4*)(dhb + 512);
    const float4 d3 = *(const float4*)(dhb + 768);

    float m = -INFINITY, l = 0.f;
    float4 c0 = make_float4(0.f, 0.f, 0.f, 0.f);
    float4 c1 = c0, c2 = c0, c3 = c0;

    const int s0 = chunk * ROWS_PER_CHUNK + wave * ROWS_PER_WAVE;
    const size_t rs = (size_t)BB * EE;   // row stride in floats
    const float* rp = ingr + ((size_t)s0 * BB + b) * EE + (lane << 2);

    // preload batch 0 (rows 0,1)
    float4 xa0 = *(const float4*)(rp);
    float4 xa1 = *(const float4*)(rp + 256);
    float4 xa2 = *(const float4*)(rp + 512);
    float4 xa3 = *(const float4*)(rp + 768);
    float4 xb0 = *(const float4*)(rp + rs);
    float4 xb1 = *(const float4*)(rp + rs + 256);
    float4 xb2 = *(const float4*)(rp + rs + 512);
    float4 xb3 = *(const float4*)(rp + rs + 768);

    const int NB = ROWS_PER_WAVE / 2;    // 16 batches
    for (int jb = 0; jb < NB; ++jb) {
        // prefetch next batch (last batch re-reads current rows; L2-hit)
        const float* np = (jb < NB - 1) ? rp + 2 * rs : rp;
        float4 ya0 = *(const float4*)(np);
        float4 ya1 = *(const float4*)(np + 256);
        float4 ya2 = *(const float4*)(np + 512);
        float4 ya3 = *(const float4*)(np + 768);
        float4 yb0 = *(const float4*)(np + rs);
        float4 yb1 = *(const float4*)(np + rs + 256);
        float4 yb2 = *(const float4*)(np + rs + 512);
        float4 yb3 = *(const float4*)(np + rs + 768);

        float pa = fmaf(xa0.x, d0.x, fmaf(xa0.y, d0.y, fmaf(xa0.z, d0.z, xa0.w * d0.w)));
        pa = fmaf(xa1.x, d1.x, fmaf(xa1.y, d1.y, fmaf(xa1.z, d1.z, fmaf(xa1.w, d1.w, pa))));
        float pa2 = fmaf(xa2.x, d2.x, fmaf(xa2.y, d2.y, fmaf(xa2.z, d2.z, xa2.w * d2.w)));
        pa2 = fmaf(xa3.x, d3.x, fmaf(xa3.y, d3.y, fmaf(xa3.z, d3.z, fmaf(xa3.w, d3.w, pa2))));
        pa += pa2;
        float pb = fmaf(xb0.x, d0.x, fmaf(xb0.y, d0.y, fmaf(xb0.z, d0.z, xb0.w * d0.w)));
        pb = fmaf(xb1.x, d1.x, fmaf(xb1.y, d1.y, fmaf(xb1.z, d1.z, fmaf(xb1.w, d1.w, pb))));
        float pb2 = fmaf(xb2.x, d2.x, fmaf(xb2.y, d2.y, fmaf(xb2.z, d2.z, xb2.w * d2.w)));
        pb2 = fmaf(xb3.x, d3.x, fmaf(xb3.y, d3.y, fmaf(xb3.z, d3.z, fmaf(xb3.w, d3.w, pb2))));
        pb += pb2;

        // dual butterfly reduce (independent chains interleave in the DS pipe)
#pragma unroll
        for (int off = 32; off; off >>= 1) {
            pa += __shfl_xor(pa, off);
            pb += __shfl_xor(pb, off);
        }

        const float mn = fmaxf(m, fmaxf(pa, pb));
        const float al = __expf(m - mn);    // m=-inf first batch -> al=0
        const float ea = __expf(pa - mn);
        const float eb = __expf(pb - mn);
        l = fmaf(l, al, ea + eb);
        c0.x = fmaf(eb, xb0.x, fmaf(ea, xa0.x, c0.x * al));
        c0.y = fmaf(eb, xb0.y, fmaf(ea, xa0.y, c0.y * al));
        c0.z = fmaf(eb, xb0.z, fmaf(ea, xa0.z, c0.z * al));
        c0.w = fmaf(eb, xb0.w, fmaf(ea, xa0.w, c0.w * al));
        c1.x = fmaf(eb, xb1.x, fmaf(ea, xa1.x, c1.x * al));
        c1.y = fmaf(eb, xb1.y, fmaf(ea, xa1.y, c1.y * al));
        c1.z = fmaf(eb, xb1.z, fmaf(ea, xa1.z, c1.z * al));
        c1.w = fmaf(eb, xb1.w, fmaf(ea, xa1.w, c1.w * al));
        c2.x = fmaf(eb, xb2.x, fmaf(ea, xa2.x, c2.x * al));
        c2.y = fmaf(eb, xb2.y, fmaf(ea, xa2.y, c2.y * al));
        c2.z = fmaf(eb, xb2.z, fmaf(ea, xa2.z, c2.z * al));
        c2.w = fmaf(eb, xb2.w, fmaf(ea, xa2.w, c2.w * al));
        c3.x = fmaf(eb, xb3.x, fmaf(ea, xa3.x, c3.x * al));
        c3.y = fmaf(eb, xb3.y, fmaf(ea, xa3.y, c3.y * al));
        c3.z = fmaf(eb, xb3.z, fmaf(ea, xa3.z, c3.z * al));
        c3.w = fmaf(eb, xb3.w, fmaf(ea, xa3.w, c3.w * al));
        m = mn;

        xa0 = ya0; xa1 = ya1; xa2 = ya2; xa3 = ya3;
        xb0 = yb0; xb1 = yb1; xb2 = yb2; xb3 = yb3;
        rp = np;
    }

    // Combine 4 wave-partials through LDS (once per block).
    __shared__ float cbuf[NWAVES][EE];   // 16 KB
    __shared__ float smm[NWAVES], sll[NWAVES];
    float4* cw = (float4*)&cbuf[wave][0];
    cw[lane] = c0;
    cw[64 + lane] = c1;
    cw[128 + lane] = c2;
    cw[192 + lane] = c3;
    if (lane == 0) { smm[wave] = m; sll[wave] = l; }
    __syncthreads();

    const float M = fmaxf(fmaxf(smm[0], smm[1]), fmaxf(smm[2], smm[3]));
    const float w0 = __expf(smm[0] - M);
    const float w1 = __expf(smm[1] - M);
    const float w2 = __expf(smm[2] - M);
    const float w3 = __expf(smm[3] - M);
    const float L = sll[0] * w0 + sll[1] * w1 + sll[2] * w2 + sll[3] * w3;

    float4 a0 = ((const float4*)&cbuf[0][0])[tid];
    float4 a1 = ((const float4*)&cbuf[1][0])[tid];
    float4 a2 = ((const float4*)&cbuf[2][0])[tid];
    float4 a3 = ((const float4*)&cbuf[3][0])[tid];
    float4 r;
    r.x = a0.x * w0 + a1.x * w1 + a2.x * w2 + a3.x * w3;
    r.y = a0.y * w0 + a1.y * w1 + a2.y * w2 + a3.y * w3;
    r.z = a0.z * w0 + a1.z * w1 + a2.z * w2 + a3.z * w3;
    r.w = a0.w * w0 + a1.w * w1 + a2.w * w2 + a3.w * w3;

    float4* dst = (float4*)(pctx + ((size_t)b * NCHUNK + chunk) * EE);
    dst[tid] = r;
    if (tid == 0) {
        pml[((size_t)b * NCHUNK + chunk) * 2] = M;
        pml[((size_t)b * NCHUNK + chunk) * 2 + 1] = L;
    }
}

// Merge the NCHUNK partials per b, normalize, build concat[b,0:2048].
__global__ __launch_bounds__(256) void combine_kernel(
        const float* __restrict__ pctx,  // [B,NCHUNK,E]
        const float* __restrict__ pml,   // [B,NCHUNK,2]
        const float* __restrict__ dec,   // [B,DH]
        float* __restrict__ concat)      // [B, E+DH]
{
    const int b = blockIdx.x;
    const int tid = threadIdx.x;
    float M = -INFINITY;
#pragma unroll
    for (int c = 0; c < NCHUNK; ++c)
        M = fmaxf(M, pml[((size_t)b * NCHUNK + c) * 2]);
    float w[NCHUNK];
    float L = 0.f;
#pragma unroll
    for (int c = 0; c < NCHUNK; ++c) {
        w[c] = __expf(pml[((size_t)b * NCHUNK + c) * 2] - M);
        L += pml[((size_t)b * NCHUNK + c) * 2 + 1] * w[c];
    }
    const float invL = 1.f / L;
    float4 r = make_float4(0.f, 0.f, 0.f, 0.f);
#pragma unroll
    for (int c = 0; c < NCHUNK; ++c) {
        float4 v = ((const float4*)(pctx + ((size_t)b * NCHUNK + c) * EE))[tid];
        r.x = fmaf(v.x, w[c], r.x);
        r.y = fmaf(v.y, w[c], r.y);
        r.z = fmaf(v.z, w[c], r.z);
        r.w = fmaf(v.w, w[c], r.w);
    }
    r.x *= invL; r.y *= invL; r.z *= invL; r.w *= invL;
    float* crow = concat + (size_t)b * (EE + DHH);
    ((float4*)crow)[tid] = r;
    float4 dv = ((const float4*)(dec + (size_t)b * DHH))[tid];
    ((float4*)(crow + EE))[tid] = dv;
}

extern "C" void kernel_launch(void* const* d_in, const int* in_sizes, int n_in,
                              void* d_out, int out_size, void* d_ws, size_t ws_size,
                              hipStream_t stream) {
    const float* ingr = (const float*)d_in[0];  // [S,B,E]
    const float* dec  = (const float*)d_in[1];  // [1,B,DH]
    const float* Wp   = (const float*)d_in[2];  // [E,DH]
    const float* bp   = (const float*)d_in[3];  // [E]
    const float* Wo   = (const float*)d_in[4];  // [OUT,E+DH]
    const float* bo   = (const float*)d_in[5];  // [OUT]
    float* out = (float*)d_out;                 // [1,B,OUT]

    // workspace layout (fp32): dh | pctx | pml | concat | part1 | part2  (~22 MB)
    float* dhbuf  = (float*)d_ws;                          // B*E
    float* pctx   = dhbuf + (size_t)BB * EE;               // B*NCHUNK*E
    float* pml    = pctx + (size_t)BB * NCHUNK * EE;       // B*NCHUNK*2
    float* concat = pml + (size_t)BB * NCHUNK * 2;         // B*(E+DH)
    float* part1  = concat + (size_t)BB * (EE + DHH);      // Z*B*E
    float* part2  = part1 + (size_t)ZSPLIT * BB * EE;      // Z*B*OUT

    const int MN4 = BB * EE / 4;   // 32768 float4 outputs per GEMM

    // 1) dh = dec @ W_proj^T + b_proj   (partials + reduce, no atomics)
    gemm_nt_partk<<<dim3(EE / 64, BB / 64, ZSPLIT), 256, 0, stream>>>(
        dec, Wp, part1, BB, EE, DHH, DHH / ZSPLIT);
    reduce_splitk<<<MN4 / 256, 256, 0, stream>>>(part1, bp, dhbuf, MN4, ZSPLIT);

    // 2) single-pass flash attention over ingr
    flash_attn_kernel<<<dim3(NCHUNK, BB), 256, 0, stream>>>(ingr, dhbuf, pctx, pml);

    // 3) merge partials, build concat = [context, dec]
    combine_kernel<<<BB, 256, 0, stream>>>(pctx, pml, dec, concat);

    // 4) out = concat @ W_out^T + b_out
    gemm_nt_partk<<<dim3(OO / 64, BB / 64, ZSPLIT), 256, 0, stream>>>(
        concat, Wo, part2, BB, OO, EE + DHH, (EE + DHH) / ZSPLIT);
    reduce_splitk<<<MN4 / 256, 256, 0, stream>>>(part2, bo, out, MN4, ZSPLIT);
}